// Round 6
// baseline (893.520 us; speedup 1.0000x reference)
//
#include <hip/hip_runtime.h>
#include <math.h>

#define NROWS 50000
#define DIN   3000
#define FH1   100
#define FH2   20
#define GH1   32
#define GH2   8
#define KCL   10
#define LAT   28
#define NEDGE 800000

static __device__ __forceinline__ float elu1(float v) {
  return v > 0.f ? v : (__expf(v) - 1.f);
}

static __device__ __forceinline__ unsigned short f2bf(float f) {
  unsigned int u = __float_as_uint(f);
  unsigned int r = (u + 0x7FFFu + ((u >> 16) & 1u)) >> 16;
  return (unsigned short)r;
}

#define BN_RS 0.99995000374968754f  /* 1/sqrt(1+1e-4) */

typedef __attribute__((ext_vector_type(8))) short bf16x8_t;
typedef __attribute__((ext_vector_type(4))) float f32x4_t;

// ---------------- prep: Wt[n][k] = bf16(W1[k][n]), n<112 (pad0), k<3008 (pad0) ----------------
__global__ __launch_bounds__(256) void k_prepW(const float* __restrict__ W,
                                               unsigned short* __restrict__ Wt) {
  const int idx = blockIdx.x * 256 + threadIdx.x;   // 112*376 chunks of 8
  const int n = idx / 376;
  const int kc = (idx - n * 376) * 8;
  if (n >= 112) return;
  unsigned short v[8];
#pragma unroll
  for (int j = 0; j < 8; ++j) {
    const int k = kc + j;
    const float f = (n < FH1 && k < DIN) ? W[(size_t)k * FH1 + n] : 0.f;
    v[j] = f2bf(f);
  }
  uint4 pv;
  pv.x = (unsigned)v[0] | ((unsigned)v[1] << 16);
  pv.y = (unsigned)v[2] | ((unsigned)v[3] << 16);
  pv.z = (unsigned)v[4] | ((unsigned)v[5] << 16);
  pv.w = (unsigned)v[6] | ((unsigned)v[7] << 16);
  *(uint4*)&Wt[(size_t)n * 3008 + kc] = pv;
}

// ---------------- GEMM1 v5: LDS-free MFMA, named-register load pipeline ----------------
// Root cause of v3/v4 slowness: compiler allocated tiny VGPR budgets (36/80) and
// serialized every load into load->vmcnt(0)->consume chains (~6 round-trips/K-step).
// v5: all 7 B loads in named regs issued at step top; A prefetched 3 steps ahead into
// rotating named slots (manual 3-step unroll, zero-copy rotation); launch_bounds(256,4)
// raises VGPR cap to 128 (need ~96).
__global__ __launch_bounds__(256, 4) void k_gemm1(
    const float* __restrict__ x, const unsigned short* __restrict__ Wt,
    const float* __restrict__ b1, const float* __restrict__ g1, const float* __restrict__ bb1,
    float* __restrict__ out)
{
  const int tid = threadIdx.x;
  const int w = tid >> 6, lane = tid & 63;
  const int fr = lane & 15;
  const int fk = (lane >> 4) * 8;          // k-slice base 0,8,16,24
  const int rowBase = blockIdx.x * 64;

  const int myRow = rowBase + w * 16 + fr;
  const int rowc = myRow < NROWS ? myRow : (NROWS - 1);   // clamp: keep address legal
  const float* xrow = x + (size_t)rowc * DIN;
  const unsigned short* wtb = Wt + (size_t)fr * 3008 + fk;

  f32x4_t acc[7];
#pragma unroll
  for (int f = 0; f < 7; ++f) acc[f] = (f32x4_t){0.f, 0.f, 0.f, 0.f};

#define LOADA(d0, d1, ksv)                                         \
  {                                                                \
    const int kk_ = (ksv) * 32 + fk;                               \
    if (kk_ < DIN) {                                               \
      d0 = *(const float4*)&xrow[kk_];                             \
      d1 = *(const float4*)&xrow[kk_ + 4];                         \
    } else {                                                       \
      d0 = make_float4(0.f, 0.f, 0.f, 0.f);                        \
      d1 = d0;                                                     \
    }                                                              \
  }

  // One K-step: issue 7 named B loads (L2), pack current A (covers B latency),
  // prefetch A for ks+3 into the slot just consumed, then 7 MFMAs.
#define STEP(ksv, cA0, cA1)                                                     \
  {                                                                             \
    const int ko_ = (ksv) * 32;                                                 \
    const uint4 b0_ = *(const uint4*)&wtb[0 * (16 * 3008) + ko_];               \
    const uint4 b1_ = *(const uint4*)&wtb[1 * (16 * 3008) + ko_];               \
    const uint4 b2_ = *(const uint4*)&wtb[2 * (16 * 3008) + ko_];               \
    const uint4 b3_ = *(const uint4*)&wtb[3 * (16 * 3008) + ko_];               \
    const uint4 b4_ = *(const uint4*)&wtb[4 * (16 * 3008) + ko_];               \
    const uint4 b5_ = *(const uint4*)&wtb[5 * (16 * 3008) + ko_];               \
    const uint4 b6_ = *(const uint4*)&wtb[6 * (16 * 3008) + ko_];               \
    uint4 av_;                                                                  \
    av_.x = (unsigned)f2bf(cA0.x) | ((unsigned)f2bf(cA0.y) << 16);              \
    av_.y = (unsigned)f2bf(cA0.z) | ((unsigned)f2bf(cA0.w) << 16);              \
    av_.z = (unsigned)f2bf(cA1.x) | ((unsigned)f2bf(cA1.y) << 16);              \
    av_.w = (unsigned)f2bf(cA1.z) | ((unsigned)f2bf(cA1.w) << 16);              \
    LOADA(cA0, cA1, (ksv) + 3);                                                 \
    const bf16x8_t a_ = *(const bf16x8_t*)&av_;                                 \
    acc[0] = __builtin_amdgcn_mfma_f32_16x16x32_bf16(a_, *(const bf16x8_t*)&b0_, acc[0], 0, 0, 0); \
    acc[1] = __builtin_amdgcn_mfma_f32_16x16x32_bf16(a_, *(const bf16x8_t*)&b1_, acc[1], 0, 0, 0); \
    acc[2] = __builtin_amdgcn_mfma_f32_16x16x32_bf16(a_, *(const bf16x8_t*)&b2_, acc[2], 0, 0, 0); \
    acc[3] = __builtin_amdgcn_mfma_f32_16x16x32_bf16(a_, *(const bf16x8_t*)&b3_, acc[3], 0, 0, 0); \
    acc[4] = __builtin_amdgcn_mfma_f32_16x16x32_bf16(a_, *(const bf16x8_t*)&b4_, acc[4], 0, 0, 0); \
    acc[5] = __builtin_amdgcn_mfma_f32_16x16x32_bf16(a_, *(const bf16x8_t*)&b5_, acc[5], 0, 0, 0); \
    acc[6] = __builtin_amdgcn_mfma_f32_16x16x32_bf16(a_, *(const bf16x8_t*)&b6_, acc[6], 0, 0, 0); \
  }

  float4 a0x, a0y, a1x, a1y, a2x, a2y;
  LOADA(a0x, a0y, 0);
  LOADA(a1x, a1y, 1);
  LOADA(a2x, a2y, 2);

  // 94 steps: 0..92 in the unrolled-by-3 loop (31 iters), tail step 93.
  for (int ks = 0; ks < 93; ks += 3) {
    STEP(ks + 0, a0x, a0y);
    STEP(ks + 1, a1x, a1y);
    STEP(ks + 2, a2x, a2y);
  }
  STEP(93, a0x, a0y);
#undef STEP
#undef LOADA

  // epilogue: C/D layout col=lane&15, row=(lane>>4)*4+reg
  const int s4 = (lane >> 4) * 4;
#pragma unroll
  for (int f = 0; f < 7; ++f) {
    const int col = f * 16 + fr;
    if (col < FH1) {
      const float sc = g1[col] * BN_RS;
      const float bbv = bb1[col];
      const float bv = b1[col];
#pragma unroll
      for (int j = 0; j < 4; ++j) {
        const int row = rowBase + w * 16 + s4 + j;
        if (row < NROWS)
          out[(size_t)row * FH1 + col] = elu1((acc[f][j] + bv) * sc + bbv);
      }
    }
  }
}

// ---------------- feat_x = ELU(BN(feat1 @ W2 + b2)); t1 = feat_x @ gc1_W ----------------
__global__ __launch_bounds__(256) void k_enc2_gc1(
    const float* __restrict__ feat1, const float* __restrict__ W2, const float* __restrict__ b2,
    const float* __restrict__ g2, const float* __restrict__ bb2,
    const float* __restrict__ gc1W,
    float* __restrict__ fx_out, float* __restrict__ t1_out)
{
  const int row = blockIdx.x * blockDim.x + threadIdx.x;
  if (row >= NROWS) return;
  float f1[FH1];
  const float4* fr = (const float4*)(feat1 + (size_t)row * FH1);
#pragma unroll
  for (int i = 0; i < FH1/4; ++i) ((float4*)f1)[i] = fr[i];

  float fx[FH2];
#pragma unroll
  for (int j = 0; j < FH2; ++j) fx[j] = b2[j];
#pragma unroll
  for (int k = 0; k < FH1; ++k) {
    const float f = f1[k];
#pragma unroll
    for (int j = 0; j < FH2; ++j) fx[j] = fmaf(f, W2[k*FH2 + j], fx[j]);
  }
#pragma unroll
  for (int j = 0; j < FH2; ++j) fx[j] = elu1(fx[j] * (g2[j] * BN_RS) + bb2[j]);

  float4* fo = (float4*)(fx_out + (size_t)row * FH2);
#pragma unroll
  for (int i = 0; i < FH2/4; ++i) fo[i] = ((float4*)fx)[i];

  float t[GH1];
#pragma unroll
  for (int j = 0; j < GH1; ++j) t[j] = 0.f;
#pragma unroll
  for (int k = 0; k < FH2; ++k) {
    const float f = fx[k];
#pragma unroll
    for (int j = 0; j < GH1; ++j) t[j] = fmaf(f, gc1W[k*GH1 + j], t[j]);
  }
  float4* to = (float4*)(t1_out + (size_t)row * GH1);
#pragma unroll
  for (int i = 0; i < GH1/4; ++i) to[i] = ((float4*)t)[i];
}

// ---------------- CSR build: zero -> hist -> scan -> scatter ----------------
__global__ void k_zero_i(int* __restrict__ p, int n) {
  for (int i = blockIdx.x * blockDim.x + threadIdx.x; i < n; i += gridDim.x * blockDim.x)
    p[i] = 0;
}

__global__ void k_hist(const int* __restrict__ er, int* __restrict__ deg) {
  const int e = blockIdx.x * 256 + threadIdx.x;
  if (e < NEDGE) atomicAdd(&deg[er[e]], 1);
}

__global__ __launch_bounds__(1024) void k_scan(const int* __restrict__ deg,
                                               int* __restrict__ start) {
  __shared__ int sm[1024];
  const int t = threadIdx.x;
  const int c0 = t * 49;
  const int c1 = (c0 + 49 < NROWS) ? c0 + 49 : NROWS;
  int s = 0;
  for (int i = c0; i < c1; ++i) s += deg[i];
  sm[t] = s;
  __syncthreads();
  for (int off = 1; off < 1024; off <<= 1) {
    int v = (t >= off) ? sm[t - off] : 0;
    __syncthreads();
    sm[t] += v;
    __syncthreads();
  }
  int run = (t == 0) ? 0 : sm[t - 1];
  for (int i = c0; i < c1; ++i) { start[i] = run; run += deg[i]; }
  if (t == 0) start[NROWS] = NEDGE;
}

__global__ void k_scatter(const int* __restrict__ er, const int* __restrict__ ec,
                          const float* __restrict__ vals, const int* __restrict__ start,
                          int* __restrict__ cnt, int* __restrict__ colS,
                          float* __restrict__ valS) {
  const int e = blockIdx.x * 256 + threadIdx.x;
  if (e >= NEDGE) return;
  const int r = er[e];
  const int pos = start[r] + atomicAdd(&cnt[r], 1);
  colS[pos] = ec[e];
  valS[pos] = vals[e];
}

// ---------------- spmm1 gather: h1[r] = sum_j val*t1[col], 8 thr/row ----------------
__global__ __launch_bounds__(256) void k_spmm1g(
    const int* __restrict__ start, const int* __restrict__ colS, const float* __restrict__ valS,
    const float* __restrict__ t1, float* __restrict__ h1)
{
  const int tid = threadIdx.x;
  const int row = blockIdx.x * 32 + (tid >> 3);
  const int p = tid & 7;
  if (row >= NROWS) return;
  const int s = start[row], e = start[row + 1];
  float4 acc = make_float4(0.f, 0.f, 0.f, 0.f);
  for (int j = s; j < e; ++j) {
    const int c = colS[j];
    const float v = valS[j];
    const float4 tv = *(const float4*)&t1[(size_t)c * GH1 + p * 4];
    acc.x = fmaf(v, tv.x, acc.x);
    acc.y = fmaf(v, tv.y, acc.y);
    acc.z = fmaf(v, tv.z, acc.z);
    acc.w = fmaf(v, tv.w, acc.w);
  }
  *(float4*)&h1[(size_t)row * GH1 + p * 4] = acc;
}

// ---------------- mu_pre/lv_pre = relu(h1) @ gc2W / gc3W ----------------
__global__ __launch_bounds__(256) void k_h1gc(
    const float* __restrict__ h1, const float* __restrict__ gc2W, const float* __restrict__ gc3W,
    float* __restrict__ mp, float* __restrict__ lp)
{
  const int row = blockIdx.x * blockDim.x + threadIdx.x;
  if (row >= NROWS) return;
  float h[GH1];
  const float4* hr = (const float4*)(h1 + (size_t)row * GH1);
#pragma unroll
  for (int i = 0; i < GH1/4; ++i) ((float4*)h)[i] = hr[i];
#pragma unroll
  for (int k = 0; k < GH1; ++k) h[k] = fmaxf(h[k], 0.f);

  float m[GH2], l[GH2];
#pragma unroll
  for (int j = 0; j < GH2; ++j) { m[j] = 0.f; l[j] = 0.f; }
#pragma unroll
  for (int k = 0; k < GH1; ++k) {
    const float hv = h[k];
#pragma unroll
    for (int j = 0; j < GH2; ++j) {
      m[j] = fmaf(hv, gc2W[k*GH2 + j], m[j]);
      l[j] = fmaf(hv, gc3W[k*GH2 + j], l[j]);
    }
  }
  float4* mo = (float4*)(mp + (size_t)row * GH2);
  float4* lo = (float4*)(lp + (size_t)row * GH2);
  mo[0] = ((float4*)m)[0]; mo[1] = ((float4*)m)[1];
  lo[0] = ((float4*)l)[0]; lo[1] = ((float4*)l)[1];
}

// ---------------- spmm2 gather: mu/lv, 4 thr/row ----------------
__global__ __launch_bounds__(256) void k_spmm2g(
    const int* __restrict__ start, const int* __restrict__ colS, const float* __restrict__ valS,
    const float* __restrict__ mp, const float* __restrict__ lp,
    float* __restrict__ mu, float* __restrict__ lv)
{
  const int tid = threadIdx.x;
  const int row = blockIdx.x * 64 + (tid >> 2);
  const int p = tid & 3;
  if (row >= NROWS) return;
  const float* src = (p < 2) ? mp : lp;
  float* dst = (p < 2) ? mu : lv;
  const int off = (p & 1) * 4;
  const int s = start[row], e = start[row + 1];
  float4 acc = make_float4(0.f, 0.f, 0.f, 0.f);
  for (int j = s; j < e; ++j) {
    const int c = colS[j];
    const float v = valS[j];
    const float4 sv = *(const float4*)&src[(size_t)c * GH2 + off];
    acc.x = fmaf(v, sv.x, acc.x);
    acc.y = fmaf(v, sv.y, acc.y);
    acc.z = fmaf(v, sv.z, acc.z);
    acc.w = fmaf(v, sv.w, acc.w);
  }
  *(float4*)&dst[(size_t)row * GH2 + off] = acc;
}

// ---------------- z = [feat_x | mu]; gnn_z = mu; q = student-t ----------------
__global__ __launch_bounds__(256) void k_zq(
    const float* __restrict__ fx, const float* __restrict__ mu, const float* __restrict__ clus,
    float* __restrict__ z_o, float* __restrict__ gz_o, float* __restrict__ q_o)
{
  const int row = blockIdx.x * blockDim.x + threadIdx.x;
  if (row >= NROWS) return;
  float z[LAT];
  const float4* f4 = (const float4*)(fx + (size_t)row * FH2);
#pragma unroll
  for (int i = 0; i < FH2/4; ++i) ((float4*)z)[i] = f4[i];
  const float4* m4 = (const float4*)(mu + (size_t)row * GH2);
  ((float4*)z)[5] = m4[0];
  ((float4*)z)[6] = m4[1];

  float4* zo = (float4*)(z_o + (size_t)row * LAT);
#pragma unroll
  for (int i = 0; i < LAT/4; ++i) zo[i] = ((float4*)z)[i];
  float4* go = (float4*)(gz_o + (size_t)row * GH2);
  go[0] = m4[0]; go[1] = m4[1];

  float q[KCL];
  float ssum = 0.f;
#pragma unroll
  for (int j = 0; j < KCL; ++j) {
    float d = 0.f;
#pragma unroll
    for (int k = 0; k < LAT; ++k) {
      const float df = z[k] - clus[j*LAT + k];
      d = fmaf(df, df, d);
    }
    q[j] = 1.f / (1.f + d);
    ssum += q[j];
  }
  const float inv = 1.f / ssum;
#pragma unroll
  for (int j = 0; j < KCL; ++j) q[j] *= inv;
  float2* qo = (float2*)(q_o + (size_t)row * KCL);
#pragma unroll
  for (int i = 0; i < KCL/2; ++i) qo[i] = ((float2*)q)[i];
}

// ---------------- decoder: 16 rows x 256 cols per block, LDS-staged ----------------
__global__ __launch_bounds__(256) void k_dec(
    const float* __restrict__ z, const float* __restrict__ W, const float* __restrict__ db,
    const float* __restrict__ g3, const float* __restrict__ bb3, float* __restrict__ out)
{
  __shared__ float Ws[LAT][256];   // 28 KB
  __shared__ float zs[16 * LAT];   // 1.75 KB

  const int tid = threadIdx.x;
  const int c0  = blockIdx.x * 256;
  const int r0  = blockIdx.y * 16;

#pragma unroll
  for (int rep = 0; rep < 7; ++rep) {
    const int f4 = rep * 256 + tid;
    const int k  = f4 >> 6;
    const int cg = (f4 & 63) * 4;
    float4 v = make_float4(0.f, 0.f, 0.f, 0.f);
    if (c0 + cg < DIN) v = *(const float4*)&W[(size_t)k * DIN + c0 + cg];
    *(float4*)&Ws[k][cg] = v;
  }
  if (tid < 112) {
    *(float4*)&zs[tid * 4] = *(const float4*)&z[(size_t)r0 * LAT + tid * 4];
  }
  __syncthreads();

  const int w    = tid >> 6;
  const int lane = tid & 63;
  const int cl   = lane * 4;
  const int rloc = w * 4;

  float acc[4][4];
#pragma unroll
  for (int i = 0; i < 4; ++i)
#pragma unroll
    for (int j = 0; j < 4; ++j) acc[i][j] = 0.f;

#pragma unroll
  for (int k4 = 0; k4 < 7; ++k4) {
    float zq[4][4];
#pragma unroll
    for (int i = 0; i < 4; ++i)
      *(float4*)zq[i] = *(const float4*)&zs[(rloc + i) * LAT + k4 * 4];
#pragma unroll
    for (int kk = 0; kk < 4; ++kk) {
      const float4 wv = *(const float4*)&Ws[k4 * 4 + kk][cl];
#pragma unroll
      for (int i = 0; i < 4; ++i) {
        acc[i][0] = fmaf(zq[i][kk], wv.x, acc[i][0]);
        acc[i][1] = fmaf(zq[i][kk], wv.y, acc[i][1]);
        acc[i][2] = fmaf(zq[i][kk], wv.z, acc[i][2]);
        acc[i][3] = fmaf(zq[i][kk], wv.w, acc[i][3]);
      }
    }
  }

  if (c0 + cl >= DIN) return;
  const float4 db4 = *(const float4*)&db[c0 + cl];
  const float4 g4  = *(const float4*)&g3[c0 + cl];
  const float4 bb4 = *(const float4*)&bb3[c0 + cl];
#pragma unroll
  for (int i = 0; i < 4; ++i) {
    float4 v;
    v.x = elu1((acc[i][0] + db4.x) * (g4.x * BN_RS) + bb4.x);
    v.y = elu1((acc[i][1] + db4.y) * (g4.y * BN_RS) + bb4.y);
    v.z = elu1((acc[i][2] + db4.z) * (g4.z * BN_RS) + bb4.z);
    v.w = elu1((acc[i][3] + db4.w) * (g4.w * BN_RS) + bb4.w);
    *(float4*)&out[(size_t)(r0 + rloc + i) * DIN + c0 + cl] = v;
  }
}

extern "C" void kernel_launch(void* const* d_in, const int* in_sizes, int n_in,
                              void* d_out, int out_size, void* d_ws, size_t ws_size,
                              hipStream_t stream) {
  const float* x    = (const float*)d_in[0];
  const float* vals = (const float*)d_in[1];
  const float* W1   = (const float*)d_in[2];
  const float* b1   = (const float*)d_in[3];
  const float* g1   = (const float*)d_in[4];
  const float* bb1  = (const float*)d_in[5];
  const float* W2   = (const float*)d_in[6];
  const float* b2   = (const float*)d_in[7];
  const float* g2   = (const float*)d_in[8];
  const float* bb2  = (const float*)d_in[9];
  const float* gc1W = (const float*)d_in[10];
  const float* gc2W = (const float*)d_in[11];
  const float* gc3W = (const float*)d_in[12];
  const float* dW   = (const float*)d_in[13];
  const float* db   = (const float*)d_in[14];
  const float* g3   = (const float*)d_in[15];
  const float* bb3  = (const float*)d_in[16];
  const float* clus = (const float*)d_in[17];
  const int* erow   = (const int*)d_in[18];
  const int* ecol   = (const int*)d_in[19];

  float* out  = (float*)d_out;
  float* z_o  = out;
  float* mu_o = out + (size_t)NROWS * 28;
  float* lv_o = out + (size_t)NROWS * 36;
  float* de_o = out + (size_t)NROWS * 44;
  float* q_o  = out + (size_t)NROWS * 3044;
  float* fx_o = out + (size_t)NROWS * 3054;
  float* gz_o = out + (size_t)NROWS * 3074;

  // scratch lives inside the de_feat region (written last, fully overwritten)
  float* feat1 = de_o;                                   // [0, 100N)
  float* t1    = de_o + (size_t)NROWS * 100;             // [100N, 132N)
  float* h1    = de_o + (size_t)NROWS * 132;             // [132N, 164N)
  float* mp    = de_o + (size_t)NROWS * 164;             // [164N, 172N)
  float* lp    = de_o + (size_t)NROWS * 172;             // [172N, 180N)
  unsigned short* Wt = (unsigned short*)(de_o + (size_t)NROWS * 200);  // 112x3008 bf16 ~ [200N, 204N)
  int*   deg   = (int*)(de_o + (size_t)NROWS * 210);     // [210N, 211N)
  int*   cnt   = (int*)(de_o + (size_t)NROWS * 211);     // [211N, 212N)
  int*   startA= (int*)(de_o + (size_t)NROWS * 212);     // [212N, 214N) (50001 ints)
  int*   colS  = (int*)(de_o + (size_t)NROWS * 214);     // [214N, 230N)
  float* valS  = de_o + (size_t)NROWS * 230;             // [230N, 246N)

  k_prepW<<<dim3(165), 256, 0, stream>>>(W1, Wt);
  k_gemm1<<<dim3(782), 256, 0, stream>>>(x, Wt, b1, g1, bb1, feat1);
  k_enc2_gc1<<<dim3((NROWS + 255) / 256), 256, 0, stream>>>(feat1, W2, b2, g2, bb2, gc1W, fx_o, t1);

  // CSR build (deg & cnt contiguous -> one zero pass)
  k_zero_i<<<dim3(128), 256, 0, stream>>>(deg, 2 * NROWS);
  k_hist<<<dim3((NEDGE + 255) / 256), 256, 0, stream>>>(erow, deg);
  k_scan<<<dim3(1), 1024, 0, stream>>>(deg, startA);
  k_scatter<<<dim3((NEDGE + 255) / 256), 256, 0, stream>>>(erow, ecol, vals, startA, cnt, colS, valS);

  k_spmm1g<<<dim3((NROWS + 31) / 32), 256, 0, stream>>>(startA, colS, valS, t1, h1);
  k_h1gc<<<dim3((NROWS + 255) / 256), 256, 0, stream>>>(h1, gc2W, gc3W, mp, lp);
  k_spmm2g<<<dim3((NROWS + 63) / 64), 256, 0, stream>>>(startA, colS, valS, mp, lp, mu_o, lv_o);
  k_zq<<<dim3((NROWS + 255) / 256), 256, 0, stream>>>(fx_o, mu_o, clus, z_o, gz_o, q_o);
  k_dec<<<dim3(12, 3125), 256, 0, stream>>>(z_o, dW, db, g3, bb3, de_o);
}

// Round 7
// 655.772 us; speedup vs baseline: 1.3625x; 1.3625x over previous
//
#include <hip/hip_runtime.h>
#include <math.h>

#define NROWS 50000
#define DIN   3000
#define FH1   100
#define FH2   20
#define GH1   32
#define GH2   8
#define KCL   10
#define LAT   28
#define NEDGE 800000

static __device__ __forceinline__ float elu1(float v) {
  return v > 0.f ? v : (__expf(v) - 1.f);
}

static __device__ __forceinline__ unsigned short f2bf(float f) {
  unsigned int u = __float_as_uint(f);
  unsigned int r = (u + 0x7FFFu + ((u >> 16) & 1u)) >> 16;
  return (unsigned short)r;
}

#define BN_RS 0.99995000374968754f  /* 1/sqrt(1+1e-4) */

typedef __attribute__((ext_vector_type(8))) short bf16x8_t;
typedef __attribute__((ext_vector_type(4))) float f32x4_t;

// async global->LDS, 16B per lane, dest = wave-uniform base + lane*16
#define GLL(gp, lp)                                                              \
  __builtin_amdgcn_global_load_lds(                                              \
      (const __attribute__((address_space(1))) void*)(gp),                       \
      (__attribute__((address_space(3))) void*)(lp), 16, 0, 0)

// ---------------- prep: Wt[n][k] = bf16(W1[k][n]), n<112 (pad0), k<3008 (pad0) ----------------
__global__ __launch_bounds__(256) void k_prepW(const float* __restrict__ W,
                                               unsigned short* __restrict__ Wt) {
  const int idx = blockIdx.x * 256 + threadIdx.x;   // 112*376 chunks of 8
  const int n = idx / 376;
  const int kc = (idx - n * 376) * 8;
  if (n >= 112) return;
  unsigned short v[8];
#pragma unroll
  for (int j = 0; j < 8; ++j) {
    const int k = kc + j;
    const float f = (n < FH1 && k < DIN) ? W[(size_t)k * FH1 + n] : 0.f;
    v[j] = f2bf(f);
  }
  uint4 pv;
  pv.x = (unsigned)v[0] | ((unsigned)v[1] << 16);
  pv.y = (unsigned)v[2] | ((unsigned)v[3] << 16);
  pv.z = (unsigned)v[4] | ((unsigned)v[5] << 16);
  pv.w = (unsigned)v[6] | ((unsigned)v[7] << 16);
  *(uint4*)&Wt[(size_t)n * 3008 + kc] = pv;
}

// ---------------- GEMM1 v6: global_load_lds 2-phase double-buffered MFMA ----------------
// v4/v5 lesson: hipcc re-sinks register loads next to consumers (VGPR minimization) ->
// serialized round-trips. global_load_lds has no VGPR dest so it cannot be serialized.
// A fp32 [64][64] + B bf16 [112][64], XOR-swizzled (16B units, u^=row&7) via
// pre-swizzled GLOBAL source (linear LDS dest) + swizzled ds_read.
__global__ __launch_bounds__(256) void k_gemm1(
    const float* __restrict__ x, const unsigned short* __restrict__ Wt,
    const float* __restrict__ b1, const float* __restrict__ g1, const float* __restrict__ bb1,
    float* __restrict__ out)
{
  __shared__ float Af[2 * 4096];            // 2 x [64][64] fp32, 16KB each
  __shared__ unsigned short Bf[2 * 7168];   // 2 x [112][64] bf16, 14KB each

  const int tid = threadIdx.x;
  const int w = tid >> 6, lane = tid & 63;
  const int fr = lane & 15;
  const int fk = (lane >> 4) * 8;           // 0,8,16,24
  const int rowBase = blockIdx.x * 64;

  f32x4_t acc[7];
#pragma unroll
  for (int f = 0; f < 7; ++f) acc[f] = (f32x4_t){0.f, 0.f, 0.f, 0.f};

  // ---- staging: A tile (64 rows x 64 k fp32), 16 chunks of 1KB; wave w -> chunks w*4..w*4+3
#define STAGE_A(bb, tt)                                                          \
  {                                                                              \
    _Pragma("unroll")                                                            \
    for (int i = 0; i < 4; ++i) {                                                \
      const int c_ = w * 4 + i;                                                  \
      const int rl_ = c_ * 4 + (lane >> 4);                                      \
      const int v_ = lane & 15;                                                  \
      const int u_ = (v_ & 8) | ((v_ ^ rl_) & 7);                                \
      const int rg_ = (rowBase + rl_ < NROWS) ? rowBase + rl_ : (NROWS - 1);     \
      GLL(x + (size_t)rg_ * DIN + (tt) * 64 + u_ * 4,                            \
          (char*)&Af[(bb) * 4096] + c_ * 1024);                                  \
    }                                                                            \
  }
  // ---- staging: B tile (112 n x 64 k bf16), 14 chunks of 1KB; wave w -> {w, w+4, w+8, w+12}
#define STAGE_B(bb, tt)                                                          \
  {                                                                              \
    _Pragma("unroll")                                                            \
    for (int i = 0; i < 4; ++i) {                                                \
      const int c_ = w + i * 4;                                                  \
      if (c_ < 14) {                                                             \
        const int n_ = c_ * 8 + (lane >> 3);                                     \
        const int vb_ = lane & 7;                                                \
        const int ub_ = vb_ ^ (n_ & 7);                                          \
        GLL(Wt + (size_t)n_ * 3008 + (tt) * 64 + ub_ * 8,                        \
            (char*)&Bf[(bb) * 7168] + c_ * 1024);                                \
      }                                                                          \
    }                                                                            \
  }
  // ---- tail A (tile 46: k 2944..2999 valid, 3000..3007 zero) via masked ds_write
#define STAGE_A_TAIL(bb)                                                         \
  {                                                                              \
    _Pragma("unroll")                                                            \
    for (int j = 0; j < 4; ++j) {                                                \
      const int idx_ = tid * 4 + j;                                              \
      const int r_ = idx_ >> 4;                                                  \
      const int u_ = idx_ & 15;                                                  \
      const int kk_ = 2944 + u_ * 4;                                             \
      const int rg_ = (rowBase + r_ < NROWS) ? rowBase + r_ : (NROWS - 1);       \
      float4 val_ = make_float4(0.f, 0.f, 0.f, 0.f);                             \
      if (kk_ + 3 < DIN) val_ = *(const float4*)&x[(size_t)rg_ * DIN + kk_];     \
      const int v_ = (u_ & 8) | ((u_ ^ r_) & 7);                                 \
      *(float4*)&Af[(bb) * 4096 + r_ * 64 + v_ * 4] = val_;                      \
    }                                                                            \
  }

  STAGE_A(0, 0)
  STAGE_B(0, 0)
  __syncthreads();   // compiler emits vmcnt(0) drain before barrier

  const int r = w * 16 + fr;
  int cur = 0;

  for (int t = 0; t < 47; ++t) {
    // issue next tile's async loads first (they fly during compute)
    if (t < 46) {
      if (t + 1 == 46) { STAGE_A_TAIL(cur ^ 1) } else { STAGE_A(cur ^ 1, t + 1) }
      STAGE_B(cur ^ 1, t + 1)
    }

    // compute current tile: 2 k-halves x 7 B-frags
    const float* Ab = &Af[cur * 4096 + r * 64];
    bf16x8_t a[2];
#pragma unroll
    for (int h = 0; h < 2; ++h) {
      const int u0 = h * 8 + (fk >> 2);
      const int u1 = u0 + 1;
      const int v0 = (u0 & 8) | ((u0 ^ r) & 7);
      const int v1 = (u1 & 8) | ((u1 ^ r) & 7);
      const float4 p = *(const float4*)&Ab[v0 * 4];
      const float4 q = *(const float4*)&Ab[v1 * 4];
      uint4 av;
      av.x = (unsigned)f2bf(p.x) | ((unsigned)f2bf(p.y) << 16);
      av.y = (unsigned)f2bf(p.z) | ((unsigned)f2bf(p.w) << 16);
      av.z = (unsigned)f2bf(q.x) | ((unsigned)f2bf(q.y) << 16);
      av.w = (unsigned)f2bf(q.z) | ((unsigned)f2bf(q.w) << 16);
      a[h] = *(const bf16x8_t*)&av;
    }
#pragma unroll
    for (int f = 0; f < 7; ++f) {
      const int n = f * 16 + fr;
      const int ub0 = (fk >> 3);
#pragma unroll
      for (int h = 0; h < 2; ++h) {
        const int vb = (h * 4 + ub0) ^ (n & 7);
        const bf16x8_t b = *(const bf16x8_t*)&Bf[cur * 7168 + n * 64 + vb * 8];
        acc[f] = __builtin_amdgcn_mfma_f32_16x16x32_bf16(a[h], b, acc[f], 0, 0, 0);
      }
    }

    __syncthreads();   // drain: next-tile loads complete; all waves done reading cur
    cur ^= 1;
  }
#undef STAGE_A
#undef STAGE_B
#undef STAGE_A_TAIL

  // epilogue: C/D layout col=lane&15, row=(lane>>4)*4+reg
  const int s4 = (lane >> 4) * 4;
#pragma unroll
  for (int f = 0; f < 7; ++f) {
    const int col = f * 16 + fr;
    if (col < FH1) {
      const float sc = g1[col] * BN_RS;
      const float bbv = bb1[col];
      const float bv = b1[col];
#pragma unroll
      for (int j = 0; j < 4; ++j) {
        const int row = rowBase + w * 16 + s4 + j;
        if (row < NROWS)
          out[(size_t)row * FH1 + col] = elu1((acc[f][j] + bv) * sc + bbv);
      }
    }
  }
}

// ---------------- feat_x = ELU(BN(feat1 @ W2 + b2)); t1 = feat_x @ gc1_W ----------------
__global__ __launch_bounds__(256) void k_enc2_gc1(
    const float* __restrict__ feat1, const float* __restrict__ W2, const float* __restrict__ b2,
    const float* __restrict__ g2, const float* __restrict__ bb2,
    const float* __restrict__ gc1W,
    float* __restrict__ fx_out, float* __restrict__ t1_out)
{
  const int row = blockIdx.x * blockDim.x + threadIdx.x;
  if (row >= NROWS) return;
  float f1[FH1];
  const float4* fr = (const float4*)(feat1 + (size_t)row * FH1);
#pragma unroll
  for (int i = 0; i < FH1/4; ++i) ((float4*)f1)[i] = fr[i];

  float fx[FH2];
#pragma unroll
  for (int j = 0; j < FH2; ++j) fx[j] = b2[j];
#pragma unroll
  for (int k = 0; k < FH1; ++k) {
    const float f = f1[k];
#pragma unroll
    for (int j = 0; j < FH2; ++j) fx[j] = fmaf(f, W2[k*FH2 + j], fx[j]);
  }
#pragma unroll
  for (int j = 0; j < FH2; ++j) fx[j] = elu1(fx[j] * (g2[j] * BN_RS) + bb2[j]);

  float4* fo = (float4*)(fx_out + (size_t)row * FH2);
#pragma unroll
  for (int i = 0; i < FH2/4; ++i) fo[i] = ((float4*)fx)[i];

  float t[GH1];
#pragma unroll
  for (int j = 0; j < GH1; ++j) t[j] = 0.f;
#pragma unroll
  for (int k = 0; k < FH2; ++k) {
    const float f = fx[k];
#pragma unroll
    for (int j = 0; j < GH1; ++j) t[j] = fmaf(f, gc1W[k*GH1 + j], t[j]);
  }
  float4* to = (float4*)(t1_out + (size_t)row * GH1);
#pragma unroll
  for (int i = 0; i < GH1/4; ++i) to[i] = ((float4*)t)[i];
}

// ---------------- CSR build: zero -> hist -> scan -> scatter ----------------
__global__ void k_zero_i(int* __restrict__ p, int n) {
  for (int i = blockIdx.x * blockDim.x + threadIdx.x; i < n; i += gridDim.x * blockDim.x)
    p[i] = 0;
}

__global__ void k_hist(const int* __restrict__ er, int* __restrict__ deg) {
  const int e = blockIdx.x * 256 + threadIdx.x;
  if (e < NEDGE) atomicAdd(&deg[er[e]], 1);
}

__global__ __launch_bounds__(1024) void k_scan(const int* __restrict__ deg,
                                               int* __restrict__ start) {
  __shared__ int sm[1024];
  const int t = threadIdx.x;
  const int c0 = t * 49;
  const int c1 = (c0 + 49 < NROWS) ? c0 + 49 : NROWS;
  int s = 0;
  for (int i = c0; i < c1; ++i) s += deg[i];
  sm[t] = s;
  __syncthreads();
  for (int off = 1; off < 1024; off <<= 1) {
    int v = (t >= off) ? sm[t - off] : 0;
    __syncthreads();
    sm[t] += v;
    __syncthreads();
  }
  int run = (t == 0) ? 0 : sm[t - 1];
  for (int i = c0; i < c1; ++i) { start[i] = run; run += deg[i]; }
  if (t == 0) start[NROWS] = NEDGE;
}

__global__ void k_scatter(const int* __restrict__ er, const int* __restrict__ ec,
                          const float* __restrict__ vals, const int* __restrict__ start,
                          int* __restrict__ cnt, int* __restrict__ colS,
                          float* __restrict__ valS) {
  const int e = blockIdx.x * 256 + threadIdx.x;
  if (e >= NEDGE) return;
  const int r = er[e];
  const int pos = start[r] + atomicAdd(&cnt[r], 1);
  colS[pos] = ec[e];
  valS[pos] = vals[e];
}

// ---------------- spmm1 gather: h1[r] = sum_j val*t1[col], 8 thr/row ----------------
__global__ __launch_bounds__(256) void k_spmm1g(
    const int* __restrict__ start, const int* __restrict__ colS, const float* __restrict__ valS,
    const float* __restrict__ t1, float* __restrict__ h1)
{
  const int tid = threadIdx.x;
  const int row = blockIdx.x * 32 + (tid >> 3);
  const int p = tid & 7;
  if (row >= NROWS) return;
  const int s = start[row], e = start[row + 1];
  float4 acc = make_float4(0.f, 0.f, 0.f, 0.f);
  for (int j = s; j < e; ++j) {
    const int c = colS[j];
    const float v = valS[j];
    const float4 tv = *(const float4*)&t1[(size_t)c * GH1 + p * 4];
    acc.x = fmaf(v, tv.x, acc.x);
    acc.y = fmaf(v, tv.y, acc.y);
    acc.z = fmaf(v, tv.z, acc.z);
    acc.w = fmaf(v, tv.w, acc.w);
  }
  *(float4*)&h1[(size_t)row * GH1 + p * 4] = acc;
}

// ---------------- mu_pre/lv_pre = relu(h1) @ gc2W / gc3W ----------------
__global__ __launch_bounds__(256) void k_h1gc(
    const float* __restrict__ h1, const float* __restrict__ gc2W, const float* __restrict__ gc3W,
    float* __restrict__ mp, float* __restrict__ lp)
{
  const int row = blockIdx.x * blockDim.x + threadIdx.x;
  if (row >= NROWS) return;
  float h[GH1];
  const float4* hr = (const float4*)(h1 + (size_t)row * GH1);
#pragma unroll
  for (int i = 0; i < GH1/4; ++i) ((float4*)h)[i] = hr[i];
#pragma unroll
  for (int k = 0; k < GH1; ++k) h[k] = fmaxf(h[k], 0.f);

  float m[GH2], l[GH2];
#pragma unroll
  for (int j = 0; j < GH2; ++j) { m[j] = 0.f; l[j] = 0.f; }
#pragma unroll
  for (int k = 0; k < GH1; ++k) {
    const float hv = h[k];
#pragma unroll
    for (int j = 0; j < GH2; ++j) {
      m[j] = fmaf(hv, gc2W[k*GH2 + j], m[j]);
      l[j] = fmaf(hv, gc3W[k*GH2 + j], l[j]);
    }
  }
  float4* mo = (float4*)(mp + (size_t)row * GH2);
  float4* lo = (float4*)(lp + (size_t)row * GH2);
  mo[0] = ((float4*)m)[0]; mo[1] = ((float4*)m)[1];
  lo[0] = ((float4*)l)[0]; lo[1] = ((float4*)l)[1];
}

// ---------------- spmm2 gather: mu/lv, 4 thr/row ----------------
__global__ __launch_bounds__(256) void k_spmm2g(
    const int* __restrict__ start, const int* __restrict__ colS, const float* __restrict__ valS,
    const float* __restrict__ mp, const float* __restrict__ lp,
    float* __restrict__ mu, float* __restrict__ lv)
{
  const int tid = threadIdx.x;
  const int row = blockIdx.x * 64 + (tid >> 2);
  const int p = tid & 3;
  if (row >= NROWS) return;
  const float* src = (p < 2) ? mp : lp;
  float* dst = (p < 2) ? mu : lv;
  const int off = (p & 1) * 4;
  const int s = start[row], e = start[row + 1];
  float4 acc = make_float4(0.f, 0.f, 0.f, 0.f);
  for (int j = s; j < e; ++j) {
    const int c = colS[j];
    const float v = valS[j];
    const float4 sv = *(const float4*)&src[(size_t)c * GH2 + off];
    acc.x = fmaf(v, sv.x, acc.x);
    acc.y = fmaf(v, sv.y, acc.y);
    acc.z = fmaf(v, sv.z, acc.z);
    acc.w = fmaf(v, sv.w, acc.w);
  }
  *(float4*)&dst[(size_t)row * GH2 + off] = acc;
}

// ---------------- z = [feat_x | mu]; gnn_z = mu; q = student-t ----------------
__global__ __launch_bounds__(256) void k_zq(
    const float* __restrict__ fx, const float* __restrict__ mu, const float* __restrict__ clus,
    float* __restrict__ z_o, float* __restrict__ gz_o, float* __restrict__ q_o)
{
  const int row = blockIdx.x * blockDim.x + threadIdx.x;
  if (row >= NROWS) return;
  float z[LAT];
  const float4* f4 = (const float4*)(fx + (size_t)row * FH2);
#pragma unroll
  for (int i = 0; i < FH2/4; ++i) ((float4*)z)[i] = f4[i];
  const float4* m4 = (const float4*)(mu + (size_t)row * GH2);
  ((float4*)z)[5] = m4[0];
  ((float4*)z)[6] = m4[1];

  float4* zo = (float4*)(z_o + (size_t)row * LAT);
#pragma unroll
  for (int i = 0; i < LAT/4; ++i) zo[i] = ((float4*)z)[i];
  float4* go = (float4*)(gz_o + (size_t)row * GH2);
  go[0] = m4[0]; go[1] = m4[1];

  float q[KCL];
  float ssum = 0.f;
#pragma unroll
  for (int j = 0; j < KCL; ++j) {
    float d = 0.f;
#pragma unroll
    for (int k = 0; k < LAT; ++k) {
      const float df = z[k] - clus[j*LAT + k];
      d = fmaf(df, df, d);
    }
    q[j] = 1.f / (1.f + d);
    ssum += q[j];
  }
  const float inv = 1.f / ssum;
#pragma unroll
  for (int j = 0; j < KCL; ++j) q[j] *= inv;
  float2* qo = (float2*)(q_o + (size_t)row * KCL);
#pragma unroll
  for (int i = 0; i < KCL/2; ++i) qo[i] = ((float2*)q)[i];
}

// ---------------- decoder: 16 rows x 256 cols per block, LDS-staged ----------------
__global__ __launch_bounds__(256) void k_dec(
    const float* __restrict__ z, const float* __restrict__ W, const float* __restrict__ db,
    const float* __restrict__ g3, const float* __restrict__ bb3, float* __restrict__ out)
{
  __shared__ float Ws[LAT][256];   // 28 KB
  __shared__ float zs[16 * LAT];   // 1.75 KB

  const int tid = threadIdx.x;
  const int c0  = blockIdx.x * 256;
  const int r0  = blockIdx.y * 16;

#pragma unroll
  for (int rep = 0; rep < 7; ++rep) {
    const int f4 = rep * 256 + tid;
    const int k  = f4 >> 6;
    const int cg = (f4 & 63) * 4;
    float4 v = make_float4(0.f, 0.f, 0.f, 0.f);
    if (c0 + cg < DIN) v = *(const float4*)&W[(size_t)k * DIN + c0 + cg];
    *(float4*)&Ws[k][cg] = v;
  }
  if (tid < 112) {
    *(float4*)&zs[tid * 4] = *(const float4*)&z[(size_t)r0 * LAT + tid * 4];
  }
  __syncthreads();

  const int w    = tid >> 6;
  const int lane = tid & 63;
  const int cl   = lane * 4;
  const int rloc = w * 4;

  float acc[4][4];
#pragma unroll
  for (int i = 0; i < 4; ++i)
#pragma unroll
    for (int j = 0; j < 4; ++j) acc[i][j] = 0.f;

#pragma unroll
  for (int k4 = 0; k4 < 7; ++k4) {
    float zq[4][4];
#pragma unroll
    for (int i = 0; i < 4; ++i)
      *(float4*)zq[i] = *(const float4*)&zs[(rloc + i) * LAT + k4 * 4];
#pragma unroll
    for (int kk = 0; kk < 4; ++kk) {
      const float4 wv = *(const float4*)&Ws[k4 * 4 + kk][cl];
#pragma unroll
      for (int i = 0; i < 4; ++i) {
        acc[i][0] = fmaf(zq[i][kk], wv.x, acc[i][0]);
        acc[i][1] = fmaf(zq[i][kk], wv.y, acc[i][1]);
        acc[i][2] = fmaf(zq[i][kk], wv.z, acc[i][2]);
        acc[i][3] = fmaf(zq[i][kk], wv.w, acc[i][3]);
      }
    }
  }

  if (c0 + cl >= DIN) return;
  const float4 db4 = *(const float4*)&db[c0 + cl];
  const float4 g4  = *(const float4*)&g3[c0 + cl];
  const float4 bb4 = *(const float4*)&bb3[c0 + cl];
#pragma unroll
  for (int i = 0; i < 4; ++i) {
    float4 v;
    v.x = elu1((acc[i][0] + db4.x) * (g4.x * BN_RS) + bb4.x);
    v.y = elu1((acc[i][1] + db4.y) * (g4.y * BN_RS) + bb4.y);
    v.z = elu1((acc[i][2] + db4.z) * (g4.z * BN_RS) + bb4.z);
    v.w = elu1((acc[i][3] + db4.w) * (g4.w * BN_RS) + bb4.w);
    *(float4*)&out[(size_t)(r0 + rloc + i) * DIN + c0 + cl] = v;
  }
}

extern "C" void kernel_launch(void* const* d_in, const int* in_sizes, int n_in,
                              void* d_out, int out_size, void* d_ws, size_t ws_size,
                              hipStream_t stream) {
  const float* x    = (const float*)d_in[0];
  const float* vals = (const float*)d_in[1];
  const float* W1   = (const float*)d_in[2];
  const float* b1   = (const float*)d_in[3];
  const float* g1   = (const float*)d_in[4];
  const float* bb1  = (const float*)d_in[5];
  const float* W2   = (const float*)d_in[6];
  const float* b2   = (const float*)d_in[7];
  const float* g2   = (const float*)d_in[8];
  const float* bb2  = (const float*)d_in[9];
  const float* gc1W = (const float*)d_in[10];
  const float* gc2W = (const float*)d_in[11];
  const float* gc3W = (const float*)d_in[12];
  const float* dW   = (const float*)d_in[13];
  const float* db   = (const float*)d_in[14];
  const float* g3   = (const float*)d_in[15];
  const float* bb3  = (const float*)d_in[16];
  const float* clus = (const float*)d_in[17];
  const int* erow   = (const int*)d_in[18];
  const int* ecol   = (const int*)d_in[19];

  float* out  = (float*)d_out;
  float* z_o  = out;
  float* mu_o = out + (size_t)NROWS * 28;
  float* lv_o = out + (size_t)NROWS * 36;
  float* de_o = out + (size_t)NROWS * 44;
  float* q_o  = out + (size_t)NROWS * 3044;
  float* fx_o = out + (size_t)NROWS * 3054;
  float* gz_o = out + (size_t)NROWS * 3074;

  // scratch lives inside the de_feat region (written last, fully overwritten)
  float* feat1 = de_o;                                   // [0, 100N)
  float* t1    = de_o + (size_t)NROWS * 100;             // [100N, 132N)
  float* h1    = de_o + (size_t)NROWS * 132;             // [132N, 164N)
  float* mp    = de_o + (size_t)NROWS * 164;             // [164N, 172N)
  float* lp    = de_o + (size_t)NROWS * 172;             // [172N, 180N)
  unsigned short* Wt = (unsigned short*)(de_o + (size_t)NROWS * 200);  // 112x3008 bf16 ~ [200N, 204N)
  int*   deg   = (int*)(de_o + (size_t)NROWS * 210);     // [210N, 211N)
  int*   cnt   = (int*)(de_o + (size_t)NROWS * 211);     // [211N, 212N)
  int*   startA= (int*)(de_o + (size_t)NROWS * 212);     // [212N, 214N) (50001 ints)
  int*   colS  = (int*)(de_o + (size_t)NROWS * 214);     // [214N, 230N)
  float* valS  = de_o + (size_t)NROWS * 230;             // [230N, 246N)

  k_prepW<<<dim3(165), 256, 0, stream>>>(W1, Wt);
  k_gemm1<<<dim3(782), 256, 0, stream>>>(x, Wt, b1, g1, bb1, feat1);
  k_enc2_gc1<<<dim3((NROWS + 255) / 256), 256, 0, stream>>>(feat1, W2, b2, g2, bb2, gc1W, fx_o, t1);

  // CSR build (deg & cnt contiguous -> one zero pass)
  k_zero_i<<<dim3(128), 256, 0, stream>>>(deg, 2 * NROWS);
  k_hist<<<dim3((NEDGE + 255) / 256), 256, 0, stream>>>(erow, deg);
  k_scan<<<dim3(1), 1024, 0, stream>>>(deg, startA);
  k_scatter<<<dim3((NEDGE + 255) / 256), 256, 0, stream>>>(erow, ecol, vals, startA, cnt, colS, valS);

  k_spmm1g<<<dim3((NROWS + 31) / 32), 256, 0, stream>>>(startA, colS, valS, t1, h1);
  k_h1gc<<<dim3((NROWS + 255) / 256), 256, 0, stream>>>(h1, gc2W, gc3W, mp, lp);
  k_spmm2g<<<dim3((NROWS + 63) / 64), 256, 0, stream>>>(startA, colS, valS, mp, lp, mu_o, lv_o);
  k_zq<<<dim3((NROWS + 255) / 256), 256, 0, stream>>>(fx_o, mu_o, clus, z_o, gz_o, q_o);
  k_dec<<<dim3(12, 3125), 256, 0, stream>>>(z_o, dW, db, g3, bb3, de_o);
}